// Round 1
// baseline (723.208 us; speedup 1.0000x reference)
//
#include <hip/hip_runtime.h>
#include <hip/hip_bf16.h>

#define T_ROWS 1000000
#define D 82
#define NG 256

// ws layout (float offsets)
#define WS_CNT   0
#define WS_SUMP  256
#define WS_SUMY  512
#define WS_MEANP 768
#define WS_MEANY 1024
#define WS_SXY   1280
#define WS_SXX   1536
#define WS_SYY   1792
#define WS_FLOATS 2048

// Kernel A: each thread handles 2 consecutive rows (row-pair = 164 floats = 41 float4,
// 16B-aligned since 656 % 16 == 0). Computes pred = sqrt(sum((x1-x2)^2 * w)), stores it,
// and accumulates per-group count / sum(pred) / sum(Y) via LDS then global atomics.
__global__ __launch_bounds__(256) void pred_kernel(
    const float* __restrict__ X1, const float* __restrict__ X2,
    const float* __restrict__ Y, const float* __restrict__ W,
    const int* __restrict__ mask, float* __restrict__ pred_out,
    float* __restrict__ ws)
{
    __shared__ float lds_w[D];
    __shared__ float lds_cnt[NG], lds_sp[NG], lds_sy[NG];
    const int t = threadIdx.x;
    if (t < D) lds_w[t] = W[t];
    lds_cnt[t] = 0.f; lds_sp[t] = 0.f; lds_sy[t] = 0.f;
    __syncthreads();

    const int pair = blockIdx.x * 256 + t;
    if (pair < T_ROWS / 2) {
        const float4* __restrict__ p1 = (const float4*)(X1 + (size_t)pair * (2 * D));
        const float4* __restrict__ p2 = (const float4*)(X2 + (size_t)pair * (2 * D));
        float accA = 0.f, accB = 0.f;
        // phase 1: k=0..19 -> elements 0..79, all row A
        #pragma unroll 5
        for (int k = 0; k < 20; ++k) {
            float4 a = p1[k], b = p2[k];
            float d;
            d = a.x - b.x; accA += d * d * lds_w[4 * k + 0];
            d = a.y - b.y; accA += d * d * lds_w[4 * k + 1];
            d = a.z - b.z; accA += d * d * lds_w[4 * k + 2];
            d = a.w - b.w; accA += d * d * lds_w[4 * k + 3];
        }
        // k=20 straddles: elements 80,81 (row A), 82,83 (row B cols 0,1)
        {
            float4 a = p1[20], b = p2[20];
            float d;
            d = a.x - b.x; accA += d * d * lds_w[80];
            d = a.y - b.y; accA += d * d * lds_w[81];
            d = a.z - b.z; accB += d * d * lds_w[0];
            d = a.w - b.w; accB += d * d * lds_w[1];
        }
        // phase 2: k=21..40 -> row B cols 2..81
        #pragma unroll 5
        for (int k = 21; k < 41; ++k) {
            float4 a = p1[k], b = p2[k];
            const int c = 4 * k - 82;
            float d;
            d = a.x - b.x; accB += d * d * lds_w[c + 0];
            d = a.y - b.y; accB += d * d * lds_w[c + 1];
            d = a.z - b.z; accB += d * d * lds_w[c + 2];
            d = a.w - b.w; accB += d * d * lds_w[c + 3];
        }
        const float pA = sqrtf(accA);
        const float pB = sqrtf(accB);
        pred_out[2 * pair]     = pA;
        pred_out[2 * pair + 1] = pB;

        const int2   gg = *(const int2*)(mask + 2 * (size_t)pair);
        const float2 yy = *(const float2*)(Y + 2 * (size_t)pair);
        atomicAdd(&lds_cnt[gg.x], 1.f);  atomicAdd(&lds_cnt[gg.y], 1.f);
        atomicAdd(&lds_sp[gg.x], pA);    atomicAdd(&lds_sp[gg.y], pB);
        atomicAdd(&lds_sy[gg.x], yy.x);  atomicAdd(&lds_sy[gg.y], yy.y);
    }
    __syncthreads();
    atomicAdd(&ws[WS_CNT  + t], lds_cnt[t]);
    atomicAdd(&ws[WS_SUMP + t], lds_sp[t]);
    atomicAdd(&ws[WS_SUMY + t], lds_sy[t]);
}

__global__ void means_kernel(float* __restrict__ ws)
{
    const int g = threadIdx.x;
    const float c = ws[WS_CNT + g];
    ws[WS_MEANP + g] = ws[WS_SUMP + g] / c;
    ws[WS_MEANY + g] = ws[WS_SUMY + g] / c;
}

// Kernel B: second pass — centered products, accumulated per-group.
__global__ __launch_bounds__(256) void corr_kernel(
    const float* __restrict__ pred, const float* __restrict__ Y,
    const int* __restrict__ mask, float* __restrict__ ws)
{
    __shared__ float mP[NG], mY[NG], sxy[NG], sxx[NG], syy[NG];
    const int t = threadIdx.x;
    mP[t] = ws[WS_MEANP + t];
    mY[t] = ws[WS_MEANY + t];
    sxy[t] = 0.f; sxx[t] = 0.f; syy[t] = 0.f;
    __syncthreads();

    const int stride = gridDim.x * blockDim.x;
    for (int r = blockIdx.x * blockDim.x + t; r < T_ROWS; r += stride) {
        const int g = mask[r];
        const float xc = pred[r] - mP[g];
        const float yc = Y[r]    - mY[g];
        atomicAdd(&sxy[g], xc * yc);
        atomicAdd(&sxx[g], xc * xc);
        atomicAdd(&syy[g], yc * yc);
    }
    __syncthreads();
    atomicAdd(&ws[WS_SXY + t], sxy[t]);
    atomicAdd(&ws[WS_SXX + t], sxx[t]);
    atomicAdd(&ws[WS_SYY + t], syy[t]);
}

__global__ void final_kernel(const float* __restrict__ ws, float* __restrict__ out)
{
    __shared__ float red[NG];
    const int g = threadIdx.x;
    const float r = ws[WS_SXY + g] / sqrtf(ws[WS_SXX + g] * ws[WS_SYY + g]);
    red[g] = fabsf(r);
    __syncthreads();
    for (int s = 128; s > 0; s >>= 1) {
        if (g < s) red[g] += red[g + s];
        __syncthreads();
    }
    if (g == 0) out[0] = red[0] / (float)NG;
}

extern "C" void kernel_launch(void* const* d_in, const int* in_sizes, int n_in,
                              void* d_out, int out_size, void* d_ws, size_t ws_size,
                              hipStream_t stream)
{
    const float* X1   = (const float*)d_in[0];
    const float* X2   = (const float*)d_in[1];
    const float* Y    = (const float*)d_in[2];
    const float* W    = (const float*)d_in[3];
    const int*   mask = (const int*)d_in[4];
    float* out = (float*)d_out;
    float* ws  = (float*)d_ws;

    hipMemsetAsync(ws, 0, WS_FLOATS * sizeof(float), stream);

    const int pairs = T_ROWS / 2;                 // 500,000
    const int gridA = (pairs + 255) / 256;        // 1954
    pred_kernel<<<gridA, 256, 0, stream>>>(X1, X2, Y, W, mask, out + 1, ws);
    means_kernel<<<1, 256, 0, stream>>>(ws);
    corr_kernel<<<1024, 256, 0, stream>>>(out + 1, Y, mask, ws);
    final_kernel<<<1, 256, 0, stream>>>(ws, out);
}